// Round 15
// baseline (56.855 us; speedup 1.0000x reference)
//
#include <hip/hip_runtime.h>

// SeparateSourceDense: out[n,:] = x[n,:] @ kernel[source[n]] + bias[source[n],:]
// N=8192, F=256, OUT=256, S=16.
// Round 15: DIAGNOSTIC. r14 kernel (best, 19.66us) wrapped in REPEAT=4 with
// asm-opaque pointer offsets so the dispatch (~60us) beats the ~40us harness
// fills into rocprof top-5 WITH counters. All reps write identical values ->
// deterministic; absmax tripwire 0.03125 unchanged.

#define NROWS 8192
#define FDIM  256
#define ODIM  256
#define NSRC  16

#define BM 64
#define BN 64
#define LDA  264         // shorts per LDS row
#define LDAB 528         // bytes per LDS row (16B-aligned)
#define MCHUNKS 8
#define NWG (NSRC * MCHUNKS * 4)   // 512 blocks = exactly co-resident at 2/CU
#define REPEAT 4

typedef float f32x4 __attribute__((ext_vector_type(4)));
typedef short s16x8 __attribute__((ext_vector_type(8)));

__device__ __forceinline__ uint f2bf(float f) {
    union { float f; uint u; } v; v.f = f;              // RNE, inputs finite
    return (v.u + 0x7fffu + ((v.u >> 16) & 1u)) >> 16;
}
__device__ __forceinline__ uint pk2(float lo, float hi) {
    return f2bf(lo) | (f2bf(hi) << 16);
}
__device__ __forceinline__ float f4get(const float4& v, int k) {
    return k == 0 ? v.x : k == 1 ? v.y : k == 2 ? v.z : v.w;
}

__global__ __launch_bounds__(256) void fused_k(
        const float* __restrict__ x,
        const int* __restrict__ source,
        const float* __restrict__ kern,
        const float* __restrict__ bias,
        float* __restrict__ out) {
    // XCD-chunked swizzle: XCD c gets contiguous wg range [c*64, c*64+64)
    const int bid = blockIdx.x;
    const int wg  = (bid & 7) * (NWG / 8) + (bid >> 3);
    const int tile = wg >> 2;
    const int s    = tile / MCHUNKS;
    const int mc   = tile % MCHUNKS;
    const int n0   = (wg & 3) * BN;
    const int lo0  = mc * BM;

    const int t    = threadIdx.x;
    const int lane = t & 63;
    const int wid  = t >> 6;                    // 0..3: strip rows [16w,16w+16)

    __shared__ int   wsum[4];
    __shared__ int   rows_lds[BM];
    __shared__ short a_lds[BM * LDA];           // 33 KB
    __shared__ short b_lds[BN * LDA];           // 33 KB

    const int k0 = (t >> 4) * 16;               // 0..240
    const int o0 = (t & 15) * 4;                // 0..60
    const int lr = lane & 15;
    const int lg = lane >> 4;
    const int srow = 16 * wid + (lane >> 2);
    const int scol = (lane & 3) * 8;

    int zero;
    asm volatile("v_mov_b32 %0, 0" : "=v"(zero));

    #pragma unroll 1
    for (int rep = 0; rep < REPEAT; ++rep) {
        asm volatile("" : "+v"(zero));          // re-opaque each iteration
        const float* xp  = x + zero;
        const int*   srp = source + zero;
        const float* kp  = kern + zero;
        const float* bp  = bias + zero;
        float*       op  = out + zero;
        if (rep) __syncthreads();               // rep isolation (value-benign)

        // ---- issue source loads ----
        int4 sv[8];
        const int4* sp = (const int4*)srp + (size_t)t * 8;
        #pragma unroll
        for (int i = 0; i < 8; ++i) sv[i] = sp[i];

        // ---- issue W patch loads: 4 o x 16 k ----
        const float* wbase = kp + ((size_t)s * FDIM + k0) * ODIM + n0 + o0;
        float4 wv[16];
        #pragma unroll
        for (int i = 0; i < 16; ++i)
            wv[i] = *(const float4*)(wbase + (size_t)i * ODIM);

        // ---- scan ----
        int c = 0;
        #pragma unroll
        for (int i = 0; i < 8; ++i)
            c += (sv[i].x == s) + (sv[i].y == s) + (sv[i].z == s) + (sv[i].w == s);
        int p = c;
        #pragma unroll
        for (int d = 1; d < 64; d <<= 1) {
            const int v = __shfl_up(p, d);
            if (lane >= d) p += v;
        }
        if (lane == 63) wsum[wid] = p;
        __syncthreads();
        int r_base = p - c;
        #pragma unroll
        for (int w = 0; w < 4; ++w) if (w < wid) r_base += wsum[w];
        const int cnt = wsum[0] + wsum[1] + wsum[2] + wsum[3];
        if (cnt <= lo0) return;                 // dead block: exits on rep 0

        // ---- first scatter ----
        {
            int r = r_base;
            #pragma unroll
            for (int i = 0; i < 8; ++i) {
                const int base = t * 32 + i * 4;
                if (sv[i].x == s) { if (r >= lo0 && r < lo0 + BM) rows_lds[r - lo0] = base;     ++r; }
                if (sv[i].y == s) { if (r >= lo0 && r < lo0 + BM) rows_lds[r - lo0] = base + 1; ++r; }
                if (sv[i].z == s) { if (r >= lo0 && r < lo0 + BM) rows_lds[r - lo0] = base + 2; ++r; }
                if (sv[i].w == s) { if (r >= lo0 && r < lo0 + BM) rows_lds[r - lo0] = base + 3; ++r; }
            }
        }

        // ---- register-transpose W patch -> b_lds[o][k] ----
        #pragma unroll
        for (int j = 0; j < 4; ++j) {
            uint4 q0, q1;
            q0.x = pk2(f4get(wv[0],  j), f4get(wv[1],  j));
            q0.y = pk2(f4get(wv[2],  j), f4get(wv[3],  j));
            q0.z = pk2(f4get(wv[4],  j), f4get(wv[5],  j));
            q0.w = pk2(f4get(wv[6],  j), f4get(wv[7],  j));
            q1.x = pk2(f4get(wv[8],  j), f4get(wv[9],  j));
            q1.y = pk2(f4get(wv[10], j), f4get(wv[11], j));
            q1.z = pk2(f4get(wv[12], j), f4get(wv[13], j));
            q1.w = pk2(f4get(wv[14], j), f4get(wv[15], j));
            char* dst = (char*)b_lds + (size_t)(o0 + j) * LDAB + 2 * k0;
            *(uint4*)(dst)      = q0;
            *(uint4*)(dst + 16) = q1;
        }

        const float bv0 = bp[s * ODIM + n0 +      lr];
        const float bv1 = bp[s * ODIM + n0 + 16 + lr];
        const float bv2 = bp[s * ODIM + n0 + 32 + lr];
        const float bv3 = bp[s * ODIM + n0 + 48 + lr];

        int lo = lo0;
        __syncthreads();                        // rows_lds + b_lds published
        while (true) {
            const int nvalid = min(BM, cnt - lo);

            // ---- wave-local A stage ----
            const float* xrow = xp + (size_t)rows_lds[(srow < nvalid) ? srow : 0] * FDIM + scol;
            float4 xv[16];
            #pragma unroll
            for (int j = 0; j < 8; ++j) {
                xv[2 * j]     = *(const float4*)(xrow + j * 32);
                xv[2 * j + 1] = *(const float4*)(xrow + j * 32 + 4);
            }
            {
                short* dst = &a_lds[srow * LDA + scol];
                #pragma unroll
                for (int j = 0; j < 8; ++j) {
                    const float4 f0 = xv[2 * j];
                    const float4 f1 = xv[2 * j + 1];
                    uint4 pk;
                    pk.x = pk2(f0.x, f0.y);
                    pk.y = pk2(f0.z, f0.w);
                    pk.z = pk2(f1.x, f1.y);
                    pk.w = pk2(f1.z, f1.w);
                    *(uint4*)(dst + j * 32) = pk;
                }
            }
            asm volatile("s_waitcnt lgkmcnt(0)" ::: "memory");

            // ---- MFMA: 1x4 frags ----
            f32x4 acc0 = {}, acc1 = {}, acc2 = {}, acc3 = {};
            const short* ab = &a_lds[(16 * wid + lr) * LDA + 8 * lg];
            const short* bb = &b_lds[lr * LDA + 8 * lg];
            #pragma unroll
            for (int kk = 0; kk < 8; ++kk) {
                const s16x8 a  = *(const s16x8*)(ab + kk * 32);
                const s16x8 b0 = *(const s16x8*)(bb + kk * 32);
                const s16x8 b1 = *(const s16x8*)(bb + kk * 32 + 16 * LDA);
                const s16x8 b2 = *(const s16x8*)(bb + kk * 32 + 32 * LDA);
                const s16x8 b3 = *(const s16x8*)(bb + kk * 32 + 48 * LDA);
                acc0 = __builtin_amdgcn_mfma_f32_16x16x32_bf16(a, b0, acc0, 0, 0, 0);
                acc1 = __builtin_amdgcn_mfma_f32_16x16x32_bf16(a, b1, acc1, 0, 0, 0);
                acc2 = __builtin_amdgcn_mfma_f32_16x16x32_bf16(a, b2, acc2, 0, 0, 0);
                acc3 = __builtin_amdgcn_mfma_f32_16x16x32_bf16(a, b3, acc3, 0, 0, 0);
            }

            // ---- epilogue ----
            #pragma unroll
            for (int rr = 0; rr < 4; ++rr) {
                const int lm = 16 * wid + 4 * lg + rr;
                if (lm < nvalid) {
                    float* orow = op + (size_t)rows_lds[lm] * ODIM + n0;
                    orow[lr]      = acc0[rr] + bv0;
                    orow[lr + 16] = acc1[rr] + bv1;
                    orow[lr + 32] = acc2[rr] + bv2;
                    orow[lr + 48] = acc3[rr] + bv3;
                }
            }

            lo += BM;
            if (!(mc == MCHUNKS - 1 && lo < cnt)) break;
            __syncthreads();
            {
                int r = r_base;
                #pragma unroll
                for (int i = 0; i < 8; ++i) {
                    const int4 s2 = sp[i];
                    const int base = t * 32 + i * 4;
                    if (s2.x == s) { if (r >= lo && r < lo + BM) rows_lds[r - lo] = base;     ++r; }
                    if (s2.y == s) { if (r >= lo && r < lo + BM) rows_lds[r - lo] = base + 1; ++r; }
                    if (s2.z == s) { if (r >= lo && r < lo + BM) rows_lds[r - lo] = base + 2; ++r; }
                    if (s2.w == s) { if (r >= lo && r < lo + BM) rows_lds[r - lo] = base + 3; ++r; }
                }
            }
            __syncthreads();
        }
    }
}

// ---------------------------------------------------------------------------
extern "C" void kernel_launch(void* const* d_in, const int* in_sizes, int n_in,
                              void* d_out, int out_size, void* d_ws, size_t ws_size,
                              hipStream_t stream) {
    const float* x      = (const float*)d_in[0];
    const int*   source = (const int*)d_in[1];
    const float* kern   = (const float*)d_in[2];
    const float* bias   = (const float*)d_in[3];
    float*       out    = (float*)d_out;

    hipLaunchKernelGGL(fused_k, dim3(NWG), dim3(256), 0, stream,
                       x, source, kern, bias, out);
}

// Round 16
// 25.849 us; speedup vs baseline: 2.1995x; 2.1995x over previous
//
#include <hip/hip_runtime.h>

// SeparateSourceDense: out[n,:] = x[n,:] @ kernel[source[n]] + bias[source[n],:]
// N=8192, F=256, OUT=256, S=16.
// Round 16: DIAGNOSTIC (phase algebra). r14 kernel with the INNER phase
// (gather -> a_lds -> MFMA -> epilogue) repeated 4x via asm-opaque pointers;
// head (scan/scatter/W-transpose) runs once. With r15's head+inner = 15.1us:
//   inner = (dispatch - 15.1)/3, head = 15.1 - inner.
// All reps store identical values -> deterministic; absmax 0.03125 tripwire.

#define NROWS 8192
#define FDIM  256
#define ODIM  256
#define NSRC  16

#define BM 64
#define BN 64
#define LDA  264         // shorts per LDS row
#define LDAB 528         // bytes per LDS row (16B-aligned)
#define MCHUNKS 8
#define NWG (NSRC * MCHUNKS * 4)   // 512 blocks = exactly co-resident at 2/CU
#define REPEAT 4

typedef float f32x4 __attribute__((ext_vector_type(4)));
typedef short s16x8 __attribute__((ext_vector_type(8)));

__device__ __forceinline__ uint f2bf(float f) {
    union { float f; uint u; } v; v.f = f;              // RNE, inputs finite
    return (v.u + 0x7fffu + ((v.u >> 16) & 1u)) >> 16;
}
__device__ __forceinline__ uint pk2(float lo, float hi) {
    return f2bf(lo) | (f2bf(hi) << 16);
}
__device__ __forceinline__ float f4get(const float4& v, int k) {
    return k == 0 ? v.x : k == 1 ? v.y : k == 2 ? v.z : v.w;
}

__global__ __launch_bounds__(256) void fused_k(
        const float* __restrict__ x,
        const int* __restrict__ source,
        const float* __restrict__ kern,
        const float* __restrict__ bias,
        float* __restrict__ out) {
    // XCD-chunked swizzle: XCD c gets contiguous wg range [c*64, c*64+64)
    const int bid = blockIdx.x;
    const int wg  = (bid & 7) * (NWG / 8) + (bid >> 3);
    const int tile = wg >> 2;
    const int s    = tile / MCHUNKS;
    const int mc   = tile % MCHUNKS;
    const int n0   = (wg & 3) * BN;
    const int lo0  = mc * BM;

    const int t    = threadIdx.x;
    const int lane = t & 63;
    const int wid  = t >> 6;                    // 0..3: strip rows [16w,16w+16)

    __shared__ int   wsum[4];
    __shared__ int   rows_lds[BM];
    __shared__ short a_lds[BM * LDA];           // 33 KB
    __shared__ short b_lds[BN * LDA];           // 33 KB

    // ---- issue source loads (scan consumes first) ----
    int4 sv[8];
    const int4* sp = (const int4*)source + (size_t)t * 8;
    #pragma unroll
    for (int i = 0; i < 8; ++i) sv[i] = sp[i];

    // ---- issue W patch loads: 4 o x 16 k (coalesced 256B per k-row) ----
    const int k0 = (t >> 4) * 16;               // 0..240
    const int o0 = (t & 15) * 4;                // 0..60
    const float* wbase = kern + ((size_t)s * FDIM + k0) * ODIM + n0 + o0;
    float4 wv[16];
    #pragma unroll
    for (int i = 0; i < 16; ++i)
        wv[i] = *(const float4*)(wbase + (size_t)i * ODIM);

    // ---- scan: thread t owns rows [32t, 32t+32) ----
    int c = 0;
    #pragma unroll
    for (int i = 0; i < 8; ++i)
        c += (sv[i].x == s) + (sv[i].y == s) + (sv[i].z == s) + (sv[i].w == s);
    int p = c;
    #pragma unroll
    for (int d = 1; d < 64; d <<= 1) {
        const int v = __shfl_up(p, d);
        if (lane >= d) p += v;
    }
    if (lane == 63) wsum[wid] = p;
    __syncthreads();
    int r_base = p - c;                         // exclusive prefix in wave
    #pragma unroll
    for (int w = 0; w < 4; ++w) if (w < wid) r_base += wsum[w];
    const int cnt = wsum[0] + wsum[1] + wsum[2] + wsum[3];
    if (cnt <= lo0) return;                     // uniform: rare idle block

    // ---- first scatter (sv dies here) ----
    {
        int r = r_base;
        #pragma unroll
        for (int i = 0; i < 8; ++i) {
            const int base = t * 32 + i * 4;
            if (sv[i].x == s) { if (r >= lo0 && r < lo0 + BM) rows_lds[r - lo0] = base;     ++r; }
            if (sv[i].y == s) { if (r >= lo0 && r < lo0 + BM) rows_lds[r - lo0] = base + 1; ++r; }
            if (sv[i].z == s) { if (r >= lo0 && r < lo0 + BM) rows_lds[r - lo0] = base + 2; ++r; }
            if (sv[i].w == s) { if (r >= lo0 && r < lo0 + BM) rows_lds[r - lo0] = base + 3; ++r; }
        }
    }

    // ---- register-transpose W patch -> b_lds[o][k] (2 b128 per o-row) ----
    #pragma unroll
    for (int j = 0; j < 4; ++j) {
        uint4 q0, q1;
        q0.x = pk2(f4get(wv[0],  j), f4get(wv[1],  j));
        q0.y = pk2(f4get(wv[2],  j), f4get(wv[3],  j));
        q0.z = pk2(f4get(wv[4],  j), f4get(wv[5],  j));
        q0.w = pk2(f4get(wv[6],  j), f4get(wv[7],  j));
        q1.x = pk2(f4get(wv[8],  j), f4get(wv[9],  j));
        q1.y = pk2(f4get(wv[10], j), f4get(wv[11], j));
        q1.z = pk2(f4get(wv[12], j), f4get(wv[13], j));
        q1.w = pk2(f4get(wv[14], j), f4get(wv[15], j));
        char* dst = (char*)b_lds + (size_t)(o0 + j) * LDAB + 2 * k0;
        *(uint4*)(dst)      = q0;
        *(uint4*)(dst + 16) = q1;
    }

    const int lr = lane & 15;
    const int lg = lane >> 4;
    const int srow = 16 * wid + (lane >> 2);    // strip row this lane stages
    const int scol = (lane & 3) * 8;            // float col base (16B interleave)

    const float bv0 = bias[s * ODIM + n0 +      lr];
    const float bv1 = bias[s * ODIM + n0 + 16 + lr];
    const float bv2 = bias[s * ODIM + n0 + 32 + lr];
    const float bv3 = bias[s * ODIM + n0 + 48 + lr];

    int zero;
    asm volatile("v_mov_b32 %0, 0" : "=v"(zero));

    int lo = lo0;
    __syncthreads();                            // rows_lds + b_lds published
    while (true) {
        const int nvalid = min(BM, cnt - lo);
        const int nrep = (lo == lo0) ? REPEAT : 1;

        #pragma unroll 1
        for (int rep = 0; rep < nrep; ++rep) {
            asm volatile("" : "+v"(zero));      // re-opaque each iteration
            const float* xp = x + zero;
            float*       op = out + zero;

            // ---- wave-local A stage: gather own strip rows ----
            const float* xrow = xp + (size_t)rows_lds[(srow < nvalid) ? srow : 0] * FDIM + scol;
            float4 xv[16];
            #pragma unroll
            for (int j = 0; j < 8; ++j) {
                xv[2 * j]     = *(const float4*)(xrow + j * 32);
                xv[2 * j + 1] = *(const float4*)(xrow + j * 32 + 4);
            }
            {
                short* dst = &a_lds[srow * LDA + scol];
                #pragma unroll
                for (int j = 0; j < 8; ++j) {
                    const float4 f0 = xv[2 * j];
                    const float4 f1 = xv[2 * j + 1];
                    uint4 pk;
                    pk.x = pk2(f0.x, f0.y);
                    pk.y = pk2(f0.z, f0.w);
                    pk.z = pk2(f1.x, f1.y);
                    pk.w = pk2(f1.z, f1.w);
                    *(uint4*)(dst + j * 32) = pk;
                }
            }
            // wave-local fence (same-wave DS pipe is in-order)
            asm volatile("s_waitcnt lgkmcnt(0)" ::: "memory");

            // ---- MFMA: 1x4 frags, A rows = own strip (wave-local) ----
            f32x4 acc0 = {}, acc1 = {}, acc2 = {}, acc3 = {};
            const short* ab = &a_lds[(16 * wid + lr) * LDA + 8 * lg];
            const short* bb = &b_lds[lr * LDA + 8 * lg];
            #pragma unroll
            for (int kk = 0; kk < 8; ++kk) {
                const s16x8 a  = *(const s16x8*)(ab + kk * 32);
                const s16x8 b0 = *(const s16x8*)(bb + kk * 32);
                const s16x8 b1 = *(const s16x8*)(bb + kk * 32 + 16 * LDA);
                const s16x8 b2 = *(const s16x8*)(bb + kk * 32 + 32 * LDA);
                const s16x8 b3 = *(const s16x8*)(bb + kk * 32 + 48 * LDA);
                acc0 = __builtin_amdgcn_mfma_f32_16x16x32_bf16(a, b0, acc0, 0, 0, 0);
                acc1 = __builtin_amdgcn_mfma_f32_16x16x32_bf16(a, b1, acc1, 0, 0, 0);
                acc2 = __builtin_amdgcn_mfma_f32_16x16x32_bf16(a, b2, acc2, 0, 0, 0);
                acc3 = __builtin_amdgcn_mfma_f32_16x16x32_bf16(a, b3, acc3, 0, 0, 0);
            }

            // ---- epilogue: D[row=16w+4lg+rr][col=16b+lr]; bias + scatter ----
            #pragma unroll
            for (int rr = 0; rr < 4; ++rr) {
                const int lm = 16 * wid + 4 * lg + rr;
                if (lm < nvalid) {
                    float* orow = op + (size_t)rows_lds[lm] * ODIM + n0;
                    orow[lr]      = acc0[rr] + bv0;
                    orow[lr + 16] = acc1[rr] + bv1;
                    orow[lr + 32] = acc2[rr] + bv2;
                    orow[lr + 48] = acc3[rr] + bv3;
                }
            }
        }

        // overflow: only the last chunk loops (cnt > 512 is a rare tail)
        lo += BM;
        if (!(mc == MCHUNKS - 1 && lo < cnt)) break;
        __syncthreads();                        // all waves done with rows_lds
        {
            int r = r_base;
            #pragma unroll
            for (int i = 0; i < 8; ++i) {
                const int4 s2 = sp[i];          // reload (rare path)
                const int base = t * 32 + i * 4;
                if (s2.x == s) { if (r >= lo && r < lo + BM) rows_lds[r - lo] = base;     ++r; }
                if (s2.y == s) { if (r >= lo && r < lo + BM) rows_lds[r - lo] = base + 1; ++r; }
                if (s2.z == s) { if (r >= lo && r < lo + BM) rows_lds[r - lo] = base + 2; ++r; }
                if (s2.w == s) { if (r >= lo && r < lo + BM) rows_lds[r - lo] = base + 3; ++r; }
            }
        }
        __syncthreads();                        // new rows_lds published
    }
}

// ---------------------------------------------------------------------------
extern "C" void kernel_launch(void* const* d_in, const int* in_sizes, int n_in,
                              void* d_out, int out_size, void* d_ws, size_t ws_size,
                              hipStream_t stream) {
    const float* x      = (const float*)d_in[0];
    const int*   source = (const int*)d_in[1];
    const float* kern   = (const float*)d_in[2];
    const float* bias   = (const float*)d_in[3];
    float*       out    = (float*)d_out;

    hipLaunchKernelGGL(fused_k, dim3(NWG), dim3(256), 0, stream,
                       x, source, kern, bias, out);
}

// Round 17
// 19.405 us; speedup vs baseline: 2.9300x; 1.3321x over previous
//
#include <hip/hip_runtime.h>

// SeparateSourceDense: out[n,:] = x[n,:] @ kernel[source[n]] + bias[source[n],:]
// N=8192, F=256, OUT=256, S=16.
// Round 17: two-kernel split per r16 phase algebra (head=13us of 15, inner=2).
//   K1 prep_k (80 blocks): 0-63 W reg-transpose -> global wt bf16 [s][o][f];
//     64-79 bitmask bucketize (1 block/source) -> counts + padded rowidx.
//   K2 gemm_k (512 blocks): head = {cnt || rowidx || wt->b_lds copy} (chain
//     depth 1, no scan/scatter/transpose), then r14 inner verbatim
//     (wave-local gather + a_lds + fence + MFMA + epilogue).

#define NROWS 8192
#define FDIM  256
#define ODIM  256
#define NSRC  16

#define BM 64
#define BN 64
#define LDA  264         // shorts per LDS row
#define LDAB 528         // bytes per LDS row (16B-aligned)
#define MCHUNKS 8
#define NWG (NSRC * MCHUNKS * 4)   // 512
#define MAXC 1024                  // rowidx slots per source (>= 11 sigma)

// ws int32 layout: counts[16] | rowidx[16*1024] | wt bf16 [16][256][256]
#define WS_ROWIDX 16
#define WS_WT_INTS (16 + NSRC * MAXC)

typedef float f32x4 __attribute__((ext_vector_type(4)));
typedef short s16x8 __attribute__((ext_vector_type(8)));

__device__ __forceinline__ uint f2bf(float f) {
    union { float f; uint u; } v; v.f = f;              // RNE, inputs finite
    return (v.u + 0x7fffu + ((v.u >> 16) & 1u)) >> 16;
}
__device__ __forceinline__ uint pk2(float lo, float hi) {
    return f2bf(lo) | (f2bf(hi) << 16);
}
__device__ __forceinline__ float f4get(const float4& v, int k) {
    return k == 0 ? v.x : k == 1 ? v.y : k == 2 ? v.z : v.w;
}

// ---------------------------------------------------------------------------
// K1: prep. blocks 0..63: W transpose (s = b>>2, o-slice = (b&3)*64).
//           blocks 64..79: bucketize source s = b-64.
// ---------------------------------------------------------------------------
__global__ __launch_bounds__(256) void prep_k(
        const int* __restrict__ source,
        const float* __restrict__ kern,
        int* __restrict__ ws,
        ushort* __restrict__ wt) {
    const int b = blockIdx.x;
    const int t = threadIdx.x;

    if (b < 64) {
        // ---- W register-transpose: [s][k][o] fp32 -> [s][o][k] bf16 ----
        const int s  = b >> 2;
        const int ob = (b & 3) * 64;
        const int k0 = (t >> 4) * 16;           // 0..240
        const int o0 = ob + (t & 15) * 4;       // 4 consecutive o
        const float* wbase = kern + ((size_t)s * FDIM + k0) * ODIM + o0;
        float4 wv[16];
        #pragma unroll
        for (int i = 0; i < 16; ++i)
            wv[i] = *(const float4*)(wbase + (size_t)i * ODIM);
        #pragma unroll
        for (int j = 0; j < 4; ++j) {
            uint4 q0, q1;
            q0.x = pk2(f4get(wv[0],  j), f4get(wv[1],  j));
            q0.y = pk2(f4get(wv[2],  j), f4get(wv[3],  j));
            q0.z = pk2(f4get(wv[4],  j), f4get(wv[5],  j));
            q0.w = pk2(f4get(wv[6],  j), f4get(wv[7],  j));
            q1.x = pk2(f4get(wv[8],  j), f4get(wv[9],  j));
            q1.y = pk2(f4get(wv[10], j), f4get(wv[11], j));
            q1.z = pk2(f4get(wv[12], j), f4get(wv[13], j));
            q1.w = pk2(f4get(wv[14], j), f4get(wv[15], j));
            ushort* dst = wt + ((size_t)(s * ODIM + o0 + j)) * FDIM + k0;
            *(uint4*)(dst)     = q0;
            *(uint4*)(dst + 8) = q1;
        }
    } else {
        // ---- bucketize source s: bitmask scan + rank scatter ----
        const int s    = b - 64;
        const int lane = t & 63;
        const int wid  = t >> 6;
        __shared__ int wsum[4];

        int4 sv[8];
        const int4* sp = (const int4*)source + (size_t)t * 8;
        #pragma unroll
        for (int i = 0; i < 8; ++i) sv[i] = sp[i];

        uint mask = 0;
        #pragma unroll
        for (int i = 0; i < 8; ++i) {
            mask |= (uint)(sv[i].x == s) << (4 * i);
            mask |= (uint)(sv[i].y == s) << (4 * i + 1);
            mask |= (uint)(sv[i].z == s) << (4 * i + 2);
            mask |= (uint)(sv[i].w == s) << (4 * i + 3);
        }
        const int c = __popc(mask);
        int p = c;
        #pragma unroll
        for (int d = 1; d < 64; d <<= 1) {
            const int v = __shfl_up(p, d);
            if (lane >= d) p += v;
        }
        if (lane == 63) wsum[wid] = p;
        __syncthreads();
        int r = p - c;                          // exclusive prefix
        #pragma unroll
        for (int w = 0; w < 4; ++w) if (w < wid) r += wsum[w];
        const int cnt = wsum[0] + wsum[1] + wsum[2] + wsum[3];

        int* rg = ws + WS_ROWIDX + s * MAXC;
        uint m = mask;
        while (m) {                             // ~2 iters avg (32 rows / 16 srcs)
            const int j = __ffs(m) - 1;
            m &= m - 1;
            rg[r++] = t * 32 + j;
        }
        // tail pad with row 0 (any valid row; padded outputs are never stored)
        for (int i = cnt + t; i < MAXC; i += 256) rg[i] = 0;
        if (t == 0) ws[s] = cnt;
    }
}

// ---------------------------------------------------------------------------
// K2: grouped GEMM. Head = 3 independent loads; inner = r14 verbatim.
// ---------------------------------------------------------------------------
__global__ __launch_bounds__(256) void gemm_k(
        const float* __restrict__ x,
        const ushort* __restrict__ wt,
        const float* __restrict__ bias,
        const int* __restrict__ ws,
        float* __restrict__ out) {
    // XCD-chunked swizzle: XCD c gets contiguous wg range [c*64, c*64+64)
    const int bid = blockIdx.x;
    const int wg  = (bid & 7) * (NWG / 8) + (bid >> 3);
    const int tile = wg >> 2;
    const int s    = tile / MCHUNKS;
    const int mc   = tile % MCHUNKS;
    const int n0   = (wg & 3) * BN;
    const int lo0  = mc * BM;

    const int t    = threadIdx.x;
    const int lane = t & 63;
    const int wid  = t >> 6;                    // 0..3: strip rows [16w,16w+16)

    __shared__ int   rows_lds[BM];
    __shared__ short a_lds[BM * LDA];           // 33 KB
    __shared__ short b_lds[BN * LDA];           // 33 KB

    const int cnt = ws[s];
    if (cnt <= lo0) return;                     // rare

    // ---- head: rows_lds + b_lds, all independent loads ----
    if (t < BM) rows_lds[t] = ws[WS_ROWIDX + s * MAXC + lo0 + t];  // padded
    {
        const int br = t >> 2;                  // 0..63 (o-row)
        const int bc = (t & 3) * 64;            // shorts (128 B per thread)
        const ushort* wrow = wt + ((size_t)(s * ODIM + n0 + br)) * FDIM + bc;
        short* bdst = &b_lds[br * LDA + bc];
        #pragma unroll
        for (int j = 0; j < 8; ++j)
            *(uint4*)(bdst + 8 * j) = *(const uint4*)(wrow + 8 * j);
    }
    __syncthreads();                            // rows_lds + b_lds published

    const int lr = lane & 15;
    const int lg = lane >> 4;
    const int srow = 16 * wid + (lane >> 2);    // strip row this lane stages
    const int scol = (lane & 3) * 8;            // float col base

    const float bv0 = bias[s * ODIM + n0 +      lr];
    const float bv1 = bias[s * ODIM + n0 + 16 + lr];
    const float bv2 = bias[s * ODIM + n0 + 32 + lr];
    const float bv3 = bias[s * ODIM + n0 + 48 + lr];

    int lo = lo0;
    while (true) {
        const int nvalid = min(BM, cnt - lo);

        // ---- wave-local A stage: gather own strip rows ----
        const float* xrow = x + (size_t)rows_lds[(srow < nvalid) ? srow : 0] * FDIM + scol;
        float4 xv[16];
        #pragma unroll
        for (int j = 0; j < 8; ++j) {
            xv[2 * j]     = *(const float4*)(xrow + j * 32);
            xv[2 * j + 1] = *(const float4*)(xrow + j * 32 + 4);
        }
        {
            short* dst = &a_lds[srow * LDA + scol];
            #pragma unroll
            for (int j = 0; j < 8; ++j) {
                const float4 f0 = xv[2 * j];
                const float4 f1 = xv[2 * j + 1];
                uint4 pk;
                pk.x = pk2(f0.x, f0.y);
                pk.y = pk2(f0.z, f0.w);
                pk.z = pk2(f1.x, f1.y);
                pk.w = pk2(f1.z, f1.w);
                *(uint4*)(dst + j * 32) = pk;
            }
        }
        // wave-local fence: same-wave DS pipe is in-order
        asm volatile("s_waitcnt lgkmcnt(0)" ::: "memory");

        // ---- MFMA: 1x4 frags, A rows = own strip (wave-local) ----
        f32x4 acc0 = {}, acc1 = {}, acc2 = {}, acc3 = {};
        const short* ab = &a_lds[(16 * wid + lr) * LDA + 8 * lg];
        const short* bb = &b_lds[lr * LDA + 8 * lg];
        #pragma unroll
        for (int kk = 0; kk < 8; ++kk) {
            const s16x8 a  = *(const s16x8*)(ab + kk * 32);
            const s16x8 b0 = *(const s16x8*)(bb + kk * 32);
            const s16x8 b1 = *(const s16x8*)(bb + kk * 32 + 16 * LDA);
            const s16x8 b2 = *(const s16x8*)(bb + kk * 32 + 32 * LDA);
            const s16x8 b3 = *(const s16x8*)(bb + kk * 32 + 48 * LDA);
            acc0 = __builtin_amdgcn_mfma_f32_16x16x32_bf16(a, b0, acc0, 0, 0, 0);
            acc1 = __builtin_amdgcn_mfma_f32_16x16x32_bf16(a, b1, acc1, 0, 0, 0);
            acc2 = __builtin_amdgcn_mfma_f32_16x16x32_bf16(a, b2, acc2, 0, 0, 0);
            acc3 = __builtin_amdgcn_mfma_f32_16x16x32_bf16(a, b3, acc3, 0, 0, 0);
        }

        // ---- epilogue: D[row=16w+4lg+rr][col=16b+lr]; bias + scatter ----
        #pragma unroll
        for (int rr = 0; rr < 4; ++rr) {
            const int lm = 16 * wid + 4 * lg + rr;
            if (lm < nvalid) {
                float* orow = out + (size_t)rows_lds[lm] * ODIM + n0;
                orow[lr]      = acc0[rr] + bv0;
                orow[lr + 16] = acc1[rr] + bv1;
                orow[lr + 32] = acc2[rr] + bv2;
                orow[lr + 48] = acc3[rr] + bv3;
            }
        }

        // overflow: only the last chunk loops (cnt > 512 is a rare tail)
        lo += BM;
        if (!(mc == MCHUNKS - 1 && lo < cnt)) break;
        __syncthreads();                        // epilogue rows_lds reads done
        if (t < BM) rows_lds[t] = ws[WS_ROWIDX + s * MAXC + lo + t];
        __syncthreads();                        // new rows_lds published
    }
}

// ---------------------------------------------------------------------------
extern "C" void kernel_launch(void* const* d_in, const int* in_sizes, int n_in,
                              void* d_out, int out_size, void* d_ws, size_t ws_size,
                              hipStream_t stream) {
    const float* x      = (const float*)d_in[0];
    const int*   source = (const int*)d_in[1];
    const float* kern   = (const float*)d_in[2];
    const float* bias   = (const float*)d_in[3];
    float*       out    = (float*)d_out;

    int*    ws = (int*)d_ws;
    ushort* wt = (ushort*)(ws + WS_WT_INTS);    // 2 MB bf16 [16][256][256]

    hipLaunchKernelGGL(prep_k, dim3(80), dim3(256), 0, stream,
                       source, kern, ws, wt);
    hipLaunchKernelGGL(gemm_k, dim3(NWG), dim3(256), 0, stream,
                       x, wt, bias, ws, out);
}